// Round 16
// baseline (116.824 us; speedup 1.0000x reference)
//
#include <hip/hip_runtime.h>
#include <hip/hip_bf16.h>
#include <stdint.h>

typedef float f32x4 __attribute__((ext_vector_type(4)));
typedef short s16x8 __attribute__((ext_vector_type(8)));
typedef unsigned short u16;
typedef uint8_t u8;

#define LOG2E 1.44269504088896340736f
#define FP8MAX 448.0f   // OCP e4m3fn max normal

#if __has_builtin(__builtin_amdgcn_exp2f)
#define EXP2F __builtin_amdgcn_exp2f
#else
#define EXP2F exp2f
#endif

__device__ __forceinline__ u16 f2bf(float f) {
    union { float f; uint32_t u; } v; v.f = f;
    uint32_t r = v.u + 0x7FFFu + ((v.u >> 16) & 1u);
    return (u16)(r >> 16);
}
__device__ __forceinline__ uint32_t cvt2bf(float lo, float hi) {
    __hip_bfloat162 h = __float22bfloat162_rn(float2{lo, hi});
    union { __hip_bfloat162 h; uint32_t u; } v; v.h = h; return v.u;
}
__device__ __forceinline__ float bflo2f(uint32_t u) {
    union { uint32_t u; float f; } v; v.u = u << 16; return v.f;
}
__device__ __forceinline__ float bfhi2f(uint32_t u) {
    union { uint32_t u; float f; } v; v.u = u & 0xffff0000u; return v.f;
}
__device__ __forceinline__ uint32_t cvt4fp8(float a, float b, float c, float d) {
    int w = __builtin_amdgcn_cvt_pk_fp8_f32(a, b, 0, false);
    w     = __builtin_amdgcn_cvt_pk_fp8_f32(c, d, w, true);
    return (uint32_t)w;
}
// lgkmcnt-only workgroup barrier (global prefetches keep flying across it)
__device__ __forceinline__ void lds_barrier() {
    asm volatile("s_waitcnt lgkmcnt(0)\n\ts_barrier" ::: "memory");
}

// ---------------------------------------------------------------------------
// Kernel 1: QKV projection — load-balanced (R15, ~6us). Unchanged.
// ---------------------------------------------------------------------------
__global__ __launch_bounds__(256) void qkv_kernel(
    const float* __restrict__ x,
    const float* __restrict__ Wq, const float* __restrict__ bq,
    const float* __restrict__ Wk, const float* __restrict__ bk,
    const float* __restrict__ Wv, const float* __restrict__ bv,
    u16* __restrict__ QT, u16* __restrict__ KT, u8* __restrict__ Vg)
{
    const int tid  = threadIdx.x;
    const int lane = tid & 63;
    const int wave = tid >> 6;
    const int blk  = blockIdx.x;          // 1280 blocks
    const int b    = blk / 320;
    const int sub  = blk - b * 320;
    const int jt   = sub / 5;
    const int cg   = sub - jt * 5;
    const int j    = (jt << 6) + lane;

    const float* xb = x + (size_t)b * 64 * 4096 + j;
    float xv[64];
#pragma unroll
    for (int c = 0; c < 64; ++c) xv[c] = xb[(size_t)c * 4096];

    if (cg < 4) {
#pragma unroll
        for (int co = 0; co < 4; ++co) {
            const int row = __builtin_amdgcn_readfirstlane(cg * 16 + wave * 4 + co);
            const float* wrow = Wv + row * 64;
            float acc = bv[row];
#pragma unroll
            for (int cin = 0; cin < 64; ++cin) acc += wrow[cin] * xv[cin];
            acc = fminf(fmaxf(acc, -FP8MAX), FP8MAX);
            Vg[((size_t)(b * 64 + row)) * 4096 + j] =
                (u8)(__builtin_amdgcn_cvt_pk_fp8_f32(acc, acc, 0, false) & 0xff);
        }
    } else {
        const bool isQ = (wave < 2);
        const float* Wqk = isQ ? Wq : Wk;
        const float* bqk = isQ ? bq : bk;
        const float scl  = isQ ? LOG2E : 1.0f;
        u16* dst = isQ ? QT : KT;
        const int w2 = wave & 1;
#pragma unroll
        for (int co = 0; co < 4; ++co) {
            const int d = __builtin_amdgcn_readfirstlane(w2 * 4 + co);
            const float* wrow = Wqk + d * 64;
            float acc = bqk[d];
#pragma unroll
            for (int cin = 0; cin < 64; ++cin) acc += wrow[cin] * xv[cin];
            dst[((size_t)b * 4096 + j) * 8 + d] = f2bf(acc * scl);
        }
    }
}

// ---------------------------------------------------------------------------
// Kernel 2: flash attention, fp8 V/P, split-K, LDS-staged V, key-permuted
// S-tiles (no P LDS round-trip). R16: 128-KEY ITERATIONS — one barrier per
// 128 keys (16 -> 8 barriers), placed after subtile-0's S/exp so rendezvous
// hides behind compute. Rolling kb[4] (prefetch one SUBTILE ahead), V tile =
// 128 keys (VROW=144, 16B-aligned -> ds_write_b128 deposits). PV(u) in the
// same iteration as S(u): no cross-iteration state beyond kb/vstg (~85 regs,
// no spill — R12's 128-key attempt spilled only because P machinery existed).
// ---------------------------------------------------------------------------
#define VROW 144      // BYTES per V row (128 fp8 + 16 pad; 16 | 144)
#define OXW 65        // u32 elems per packed-Ox row

__global__ __launch_bounds__(1024, 4) void attn_kernel(
    const u16* __restrict__ QT, const u16* __restrict__ KT,
    const u8* __restrict__ Vg, const float* __restrict__ x,
    const float* __restrict__ gamma, float* __restrict__ out)
{
    __shared__ alignas(16) u8 vbuf[4][2][64 * VROW];        // 73728 B
    __shared__ uint32_t OxP[12][8 * OXW];                   // 24960 B
    __shared__ float    Lx[12 * 16];                        //   768 B ~99.5KB

    const int tid  = threadIdx.x;
    const int lane = tid & 63;
    const int wave = tid >> 6;
    const int col  = lane & 15;
    const int quad = lane >> 4;
    const int qg   = wave & 3;          // query group
    const int sp   = wave >> 2;         // key split
    const int blk  = blockIdx.x;
    const int b    = blk >> 6;
    const int i0   = (blk & 63) << 6;
    const int iw   = i0 + qg * 16;      // this wave's first query

    const u16* KTb = KT + (size_t)b * 4096 * 8;
    const u8*  Vb  = Vg + (size_t)b * 64 * 4096;

    const s16x8 z8 = {0,0,0,0,0,0,0,0};
    const f32x4 zero = {0.f, 0.f, 0.f, 0.f};

    // permuted key column for the K gather: S-tile nt covers key
    // (nt>>1)*32 + (nt&1)*4 + pcol, pcol = ((col&12)<<1) + (col&3)
    const int pcol = ((col & 12) << 1) + (col & 3);

    // Q fragment (B operand of S^T = K.Q^T): quad0 holds Q[iw+col][0..7]
    s16x8 aq = z8;
    if (quad == 0)
        aq = *(const s16x8*)(QT + ((size_t)b * 4096 + iw + col) * 8);

    f32x4 o[4];
#pragma unroll
    for (int nt = 0; nt < 4; ++nt) o[nt] = zero;
    float lsum = 0.f;

    // V staging role: 256 lanes (4 qg-waves) cover 64 rows x 8 16B chunks,
    // 2 chunks per lane (bytes c2*16 and c2*16+64 of the 128B row)
    const int slot = (qg << 6) + lane;   // 0..255
    const int srow = slot >> 2;          // 0..63
    const int c2   = slot & 3;
    const u8* vsrc = Vb + (size_t)srow * 4096 + c2 * 16;
    u8* vdst0 = &vbuf[sp][0][srow * VROW + c2 * 16];
    u8* vdst1 = &vbuf[sp][1][srow * VROW + c2 * 16];

    const int jbeg = sp << 10;

    // ---- prologue: K(u=0) frags (permuted) + stage V(iter0) -> vbuf[0] ----
    s16x8 kb[4];
#pragma unroll
    for (int nt = 0; nt < 4; ++nt) {
        s16x8 kn = z8;
        if (quad == 0)
            kn = *(const s16x8*)(KTb +
                (size_t)(jbeg + ((nt >> 1) << 5) + ((nt & 1) << 2) + pcol) * 8);
        kb[nt] = kn;
    }
    *(uint4*)(vdst0)      = *(const uint4*)(vsrc + jbeg);
    *(uint4*)(vdst0 + 64) = *(const uint4*)(vsrc + jbeg + 64);

#pragma unroll 2
    for (int t = 0; t < 8; ++t) {
        const int j0 = jbeg + (t << 7);
        const u8* vt = &vbuf[sp][t & 1][0];

        // a) stage-load V(t+1) (deposited at iteration bottom)
        uint4 vstg0, vstg1;
        if (t < 7) {
            vstg0 = *(const uint4*)(vsrc + j0 + 128);
            vstg1 = *(const uint4*)(vsrc + j0 + 192);
        }

        long long ap0, ap1;
        uint32_t w[4];
        f32x4 sv[4];

        // ---- subtile 0 (u = 2t): S, K-prefetch, exp/pack ----
#pragma unroll
        for (int nt = 0; nt < 4; ++nt)
            sv[nt] = __builtin_amdgcn_mfma_f32_16x16x32_bf16(kb[nt], aq, zero, 0, 0, 0);
#pragma unroll
        for (int nt = 0; nt < 4; ++nt) {   // K(u+1), key base j0+64
            s16x8 kn = z8;
            if (quad == 0)
                kn = *(const s16x8*)(KTb +
                    (size_t)(j0 + 64 + ((nt >> 1) << 5) + ((nt & 1) << 2) + pcol) * 8);
            kb[nt] = kn;
        }
#pragma unroll
        for (int nt = 0; nt < 4; ++nt) {
            float p0 = fminf(EXP2F(sv[nt][0]), FP8MAX);
            float p1 = fminf(EXP2F(sv[nt][1]), FP8MAX);
            float p2 = fminf(EXP2F(sv[nt][2]), FP8MAX);
            float p3 = fminf(EXP2F(sv[nt][3]), FP8MAX);
            lsum += (p0 + p1) + (p2 + p3);
            w[nt] = cvt4fp8(p0, p1, p2, p3);
        }
        ap0 = (long long)(((uint64_t)w[1] << 32) | w[0]);
        ap1 = (long long)(((uint64_t)w[3] << 32) | w[2]);

        // b) rendezvous once per 128 keys — publishes V(t); hidden behind
        //    subtile-0 compute above
        lds_barrier();

        // c) PV(2t): V frags from vbuf[t&1], subtile offset 0
#pragma unroll
        for (int nt = 0; nt < 4; ++nt) {
            long long b0 = *(const long long*)(vt + (nt * 16 + col) * VROW + quad * 8);
            long long b1 = *(const long long*)(vt + (nt * 16 + col) * VROW + quad * 8 + 32);
            o[nt] = __builtin_amdgcn_mfma_f32_16x16x32_fp8_fp8(ap0, b0, o[nt], 0, 0, 0);
            o[nt] = __builtin_amdgcn_mfma_f32_16x16x32_fp8_fp8(ap1, b1, o[nt], 0, 0, 0);
        }

        // ---- subtile 1 (u = 2t+1): S, K-prefetch(next iter), exp/pack, PV ----
#pragma unroll
        for (int nt = 0; nt < 4; ++nt)
            sv[nt] = __builtin_amdgcn_mfma_f32_16x16x32_bf16(kb[nt], aq, zero, 0, 0, 0);
        if (t < 7) {
#pragma unroll
            for (int nt = 0; nt < 4; ++nt) {   // K(u+2), key base j0+128
                s16x8 kn = z8;
                if (quad == 0)
                    kn = *(const s16x8*)(KTb +
                        (size_t)(j0 + 128 + ((nt >> 1) << 5) + ((nt & 1) << 2) + pcol) * 8);
                kb[nt] = kn;
            }
        }
#pragma unroll
        for (int nt = 0; nt < 4; ++nt) {
            float p0 = fminf(EXP2F(sv[nt][0]), FP8MAX);
            float p1 = fminf(EXP2F(sv[nt][1]), FP8MAX);
            float p2 = fminf(EXP2F(sv[nt][2]), FP8MAX);
            float p3 = fminf(EXP2F(sv[nt][3]), FP8MAX);
            lsum += (p0 + p1) + (p2 + p3);
            w[nt] = cvt4fp8(p0, p1, p2, p3);
        }
        ap0 = (long long)(((uint64_t)w[1] << 32) | w[0]);
        ap1 = (long long)(((uint64_t)w[3] << 32) | w[2]);
#pragma unroll
        for (int nt = 0; nt < 4; ++nt) {
            long long b0 = *(const long long*)(vt + (nt * 16 + col) * VROW + 64 + quad * 8);
            long long b1 = *(const long long*)(vt + (nt * 16 + col) * VROW + 64 + quad * 8 + 32);
            o[nt] = __builtin_amdgcn_mfma_f32_16x16x32_fp8_fp8(ap0, b0, o[nt], 0, 0, 0);
            o[nt] = __builtin_amdgcn_mfma_f32_16x16x32_fp8_fp8(ap1, b1, o[nt], 0, 0, 0);
        }

        // d) deposit V(t+1) into vbuf[(t+1)&1] (old occupant V(t-1) was last
        //    read before barrier b this iteration; published by next barrier)
        if (t < 7) {
            u8* vd = (t & 1) ? vdst0 : vdst1;
            *(uint4*)(vd)      = vstg0;
            *(uint4*)(vd + 64) = vstg1;
        }
    }

    // ---- reduce lsum across quads: every lane -> l[query=col] ----
    lsum += __shfl_xor(lsum, 16, 64);
    lsum += __shfl_xor(lsum, 32, 64);

    // ---- combine the 4 key-splits in LDS ----
    if (sp > 0) {
        const int slice = (sp - 1) * 4 + qg;
        uint32_t* ox = &OxP[slice][0];
#pragma unroll
        for (int nt = 0; nt < 4; ++nt) {
#pragma unroll
            for (int rp = 0; rp < 2; ++rp)
                ox[(quad * 2 + rp) * OXW + nt * 16 + col] =
                    cvt2bf(o[nt][2 * rp], o[nt][2 * rp + 1]);
        }
        if (quad == 0) Lx[slice * 16 + col] = lsum;
    }
    __syncthreads();   // full barrier: OxP/Lx cross-wave publish (once)
    if (sp == 0) {
        float ltot = lsum;
#pragma unroll
        for (int s = 0; s < 3; ++s)
            ltot += Lx[(s * 4 + qg) * 16 + col];
        float linv[4];
#pragma unroll
        for (int r = 0; r < 4; ++r)
            linv[r] = 1.0f / __shfl(ltot, quad * 4 + r, 16);

#pragma unroll
        for (int s = 0; s < 3; ++s) {
            const uint32_t* ox = &OxP[s * 4 + qg][0];
#pragma unroll
            for (int nt = 0; nt < 4; ++nt) {
#pragma unroll
                for (int rp = 0; rp < 2; ++rp) {
                    uint32_t u = ox[(quad * 2 + rp) * OXW + nt * 16 + col];
                    o[nt][2 * rp]     += bflo2f(u);
                    o[nt][2 * rp + 1] += bfhi2f(u);
                }
            }
        }
        const float g = gamma[0];
#pragma unroll
        for (int nt = 0; nt < 4; ++nt) {
            const int c = nt * 16 + col;
#pragma unroll
            for (int r = 0; r < 4; ++r) {
                const int i = iw + quad * 4 + r;
                const size_t idx = ((size_t)(b * 64 + c)) * 4096 + i;
                out[idx] = g * (o[nt][r] * linv[r]) + x[idx];
            }
        }
    }
}

// ---------------------------------------------------------------------------
extern "C" void kernel_launch(void* const* d_in, const int* in_sizes, int n_in,
                              void* d_out, int out_size, void* d_ws, size_t ws_size,
                              hipStream_t stream)
{
    const float* x     = (const float*)d_in[0];
    const float* Wq    = (const float*)d_in[1];
    const float* bq    = (const float*)d_in[2];
    const float* Wk    = (const float*)d_in[3];
    const float* bk    = (const float*)d_in[4];
    const float* Wv    = (const float*)d_in[5];
    const float* bv    = (const float*)d_in[6];
    const float* gamma = (const float*)d_in[7];

    u16* QT = (u16*)d_ws;                 // [4][4096][8]  bf16
    u16* KT = QT + (size_t)4 * 4096 * 8;  // [4][4096][8]  bf16
    u8*  Vg = (u8*)(KT + (size_t)4 * 4096 * 8);  // [4][64][4096] fp8 e4m3

    qkv_kernel<<<1280, 256, 0, stream>>>(x, Wq, bq, Wk, bk, Wv, bv, QT, KT, Vg);
    attn_kernel<<<256, 1024, 0, stream>>>(QT, KT, Vg, x, gamma, (float*)d_out);
}

// Round 17
// 96.281 us; speedup vs baseline: 1.2134x; 1.2134x over previous
//
#include <hip/hip_runtime.h>
#include <hip/hip_bf16.h>
#include <stdint.h>

typedef float f32x4 __attribute__((ext_vector_type(4)));
typedef short s16x8 __attribute__((ext_vector_type(8)));
typedef unsigned short u16;
typedef uint8_t u8;

#define LOG2E 1.44269504088896340736f
#define FP8MAX 448.0f   // OCP e4m3fn max normal

#if __has_builtin(__builtin_amdgcn_exp2f)
#define EXP2F __builtin_amdgcn_exp2f
#else
#define EXP2F exp2f
#endif

__device__ __forceinline__ u16 f2bf(float f) {
    union { float f; uint32_t u; } v; v.f = f;
    uint32_t r = v.u + 0x7FFFu + ((v.u >> 16) & 1u);
    return (u16)(r >> 16);
}
__device__ __forceinline__ uint32_t cvt2bf(float lo, float hi) {
    __hip_bfloat162 h = __float22bfloat162_rn(float2{lo, hi});
    union { __hip_bfloat162 h; uint32_t u; } v; v.h = h; return v.u;
}
__device__ __forceinline__ float bflo2f(uint32_t u) {
    union { uint32_t u; float f; } v; v.u = u << 16; return v.f;
}
__device__ __forceinline__ float bfhi2f(uint32_t u) {
    union { uint32_t u; float f; } v; v.u = u & 0xffff0000u; return v.f;
}
__device__ __forceinline__ uint32_t cvt4fp8(float a, float b, float c, float d) {
    int w = __builtin_amdgcn_cvt_pk_fp8_f32(a, b, 0, false);
    w     = __builtin_amdgcn_cvt_pk_fp8_f32(c, d, w, true);
    return (uint32_t)w;
}
__device__ __forceinline__ void ds_write16(u8* d, uint4 v) {
    uint2 lo; lo.x = v.x; lo.y = v.y;
    uint2 hi; hi.x = v.z; hi.y = v.w;
    *(uint2*)(d)     = lo;
    *(uint2*)(d + 8) = hi;
}
// lgkmcnt-only workgroup barrier (global prefetches keep flying across it)
__device__ __forceinline__ void lds_barrier() {
    asm volatile("s_waitcnt lgkmcnt(0)\n\ts_barrier" ::: "memory");
}

// ---------------------------------------------------------------------------
// Kernel 1: QKV projection — load-balanced over all 80 output rows (R15).
// 5 row-groups of 16 (4 V + 1 QK); every wave computes exactly 4 rows.
// Grid 4 x 64 x 5 = 1280 blocks x 256 threads. ~6us.
// ---------------------------------------------------------------------------
__global__ __launch_bounds__(256) void qkv_kernel(
    const float* __restrict__ x,
    const float* __restrict__ Wq, const float* __restrict__ bq,
    const float* __restrict__ Wk, const float* __restrict__ bk,
    const float* __restrict__ Wv, const float* __restrict__ bv,
    u16* __restrict__ QT, u16* __restrict__ KT, u8* __restrict__ Vg)
{
    const int tid  = threadIdx.x;
    const int lane = tid & 63;
    const int wave = tid >> 6;
    const int blk  = blockIdx.x;          // 1280 blocks
    const int b    = blk / 320;
    const int sub  = blk - b * 320;
    const int jt   = sub / 5;
    const int cg   = sub - jt * 5;
    const int j    = (jt << 6) + lane;

    const float* xb = x + (size_t)b * 64 * 4096 + j;
    float xv[64];
#pragma unroll
    for (int c = 0; c < 64; ++c) xv[c] = xb[(size_t)c * 4096];

    if (cg < 4) {
#pragma unroll
        for (int co = 0; co < 4; ++co) {
            const int row = __builtin_amdgcn_readfirstlane(cg * 16 + wave * 4 + co);
            const float* wrow = Wv + row * 64;
            float acc = bv[row];
#pragma unroll
            for (int cin = 0; cin < 64; ++cin) acc += wrow[cin] * xv[cin];
            acc = fminf(fmaxf(acc, -FP8MAX), FP8MAX);
            Vg[((size_t)(b * 64 + row)) * 4096 + j] =
                (u8)(__builtin_amdgcn_cvt_pk_fp8_f32(acc, acc, 0, false) & 0xff);
        }
    } else {
        const bool isQ = (wave < 2);
        const float* Wqk = isQ ? Wq : Wk;
        const float* bqk = isQ ? bq : bk;
        const float scl  = isQ ? LOG2E : 1.0f;
        u16* dst = isQ ? QT : KT;
        const int w2 = wave & 1;
#pragma unroll
        for (int co = 0; co < 4; ++co) {
            const int d = __builtin_amdgcn_readfirstlane(w2 * 4 + co);
            const float* wrow = Wqk + d * 64;
            float acc = bqk[d];
#pragma unroll
            for (int cin = 0; cin < 64; ++cin) acc += wrow[cin] * xv[cin];
            dst[((size_t)b * 4096 + j) * 8 + d] = f2bf(acc * scl);
        }
    }
}

// ---------------------------------------------------------------------------
// Kernel 2: flash attention — R14/R15 best body (attn ~24us). fp8 V/P,
// split-K in-block, LDS-staged V (72-B rows: stride 18 words, near-conflict-
// free), key-permuted S-tiles so the packed exp results ARE the PV
// A-fragment (P never touches LDS). 64-key iterations, one lgkmcnt-only
// barrier each. R16's 128-key variant REGRESSED (35MB spill + VROW=144
// stride-36-word bank conflicts 2.7M): do not revisit without a register
// plan and a 72-B-compatible layout.
// ---------------------------------------------------------------------------
#define VROW 72       // BYTES per V-tile row (64 fp8 + 8 pad; 8 | 72)
#define OXW 65        // u32 elems per packed-Ox row

__global__ __launch_bounds__(1024, 4) void attn_kernel(
    const u16* __restrict__ QT, const u16* __restrict__ KT,
    const u8* __restrict__ Vg, const float* __restrict__ x,
    const float* __restrict__ gamma, float* __restrict__ out)
{
    __shared__ alignas(16) u8 vbuf[4][2][64 * VROW];        // 36864 B
    __shared__ uint32_t OxP[12][8 * OXW];                   // 24960 B
    __shared__ float    Lx[12 * 16];                        //   768 B ~62.6KB

    const int tid  = threadIdx.x;
    const int lane = tid & 63;
    const int wave = tid >> 6;
    const int col  = lane & 15;
    const int quad = lane >> 4;
    const int qg   = wave & 3;          // query group
    const int sp   = wave >> 2;         // key split
    const int blk  = blockIdx.x;
    const int b    = blk >> 6;
    const int i0   = (blk & 63) << 6;
    const int iw   = i0 + qg * 16;      // this wave's first query

    const u16* KTb = KT + (size_t)b * 4096 * 8;
    const u8*  Vb  = Vg + (size_t)b * 64 * 4096;

    const s16x8 z8 = {0,0,0,0,0,0,0,0};
    const f32x4 zero = {0.f, 0.f, 0.f, 0.f};

    // permuted key column for the K gather
    const int pcol = ((col & 12) << 1) + (col & 3);

    // Q fragment (B operand of S^T = K.Q^T): quad0 holds Q[iw+col][0..7]
    s16x8 aq = z8;
    if (quad == 0)
        aq = *(const s16x8*)(QT + ((size_t)b * 4096 + iw + col) * 8);

    f32x4 o[4];
#pragma unroll
    for (int nt = 0; nt < 4; ++nt) o[nt] = zero;
    float lsum = 0.f;

    // V staging role: 4 qg-waves x 64 lanes cover 64 rows x 4 16B chunks
    const int srow = (qg << 4) + (lane >> 2);
    const int schk = lane & 3;
    const u8* vsrc = Vb + (size_t)srow * 4096 + schk * 16;
    u8* vdst0 = &vbuf[sp][0][srow * VROW + schk * 16];
    u8* vdst1 = &vbuf[sp][1][srow * VROW + schk * 16];

    const int jbeg = sp << 10;

    // ---- prologue: K(0) frags (permuted) + stage V(0) into vbuf[sp][0] ----
    s16x8 kb[4];
#pragma unroll
    for (int nt = 0; nt < 4; ++nt) {
        s16x8 kn = z8;
        if (quad == 0)
            kn = *(const s16x8*)(KTb +
                (size_t)(jbeg + ((nt >> 1) << 5) + ((nt & 1) << 2) + pcol) * 8);
        kb[nt] = kn;
    }
    ds_write16(vdst0, *(const uint4*)(vsrc + jbeg));

#pragma unroll 2
    for (int t = 0; t < 16; ++t) {
        const int j0 = jbeg + (t << 6);

        // a) stage-load V(t+1) (consumed post-barrier next iteration)
        uint4 vstg;
        if (t < 15) vstg = *(const uint4*)(vsrc + j0 + 64);

        // b) S^T(t): A = K (m=permuted key), B = Q (n=query)
        f32x4 s[4];
#pragma unroll
        for (int nt = 0; nt < 4; ++nt)
            s[nt] = __builtin_amdgcn_mfma_f32_16x16x32_bf16(kb[nt], aq, zero, 0, 0, 0);

        // c) prefetch K(t+1) (permuted)
        if (t < 15) {
#pragma unroll
            for (int nt = 0; nt < 4; ++nt) {
                s16x8 kn = z8;
                if (quad == 0)
                    kn = *(const s16x8*)(KTb +
                        (size_t)(j0 + 64 + ((nt >> 1) << 5) + ((nt & 1) << 2) + pcol) * 8);
                kb[nt] = kn;
            }
        }

        // d) P(t) = min(exp2(S),448); lsum; pack -> PV A-frags IN REGISTERS
        uint32_t w[4];
#pragma unroll
        for (int nt = 0; nt < 4; ++nt) {
            float p0 = fminf(EXP2F(s[nt][0]), FP8MAX);
            float p1 = fminf(EXP2F(s[nt][1]), FP8MAX);
            float p2 = fminf(EXP2F(s[nt][2]), FP8MAX);
            float p3 = fminf(EXP2F(s[nt][3]), FP8MAX);
            lsum += (p0 + p1) + (p2 + p3);
            w[nt] = cvt4fp8(p0, p1, p2, p3);
        }
        const long long ap0 = (long long)(((uint64_t)w[1] << 32) | w[0]);
        const long long ap1 = (long long)(((uint64_t)w[3] << 32) | w[2]);

        // e) publish V(t) (deposited by all waves last iteration)
        lds_barrier();

        // f) V(t) frags from vbuf[sp][t&1] + PV(t)
        {
            const u8* vt = &vbuf[sp][t & 1][0];
#pragma unroll
            for (int nt = 0; nt < 4; ++nt) {
                long long b0 = *(const long long*)(vt + (nt * 16 + col) * VROW + quad * 8);
                long long b1 = *(const long long*)(vt + (nt * 16 + col) * VROW + quad * 8 + 32);
                o[nt] = __builtin_amdgcn_mfma_f32_16x16x32_fp8_fp8(ap0, b0, o[nt], 0, 0, 0);
                o[nt] = __builtin_amdgcn_mfma_f32_16x16x32_fp8_fp8(ap1, b1, o[nt], 0, 0, 0);
            }
        }

        // g) deposit V(t+1) into vbuf[sp][(t+1)&1]
        if (t < 15) ds_write16((t & 1) ? vdst0 : vdst1, vstg);
    }

    // ---- reduce lsum across quads: every lane -> l[query=col] ----
    lsum += __shfl_xor(lsum, 16, 64);
    lsum += __shfl_xor(lsum, 32, 64);

    // ---- combine the 4 key-splits in LDS ----
    if (sp > 0) {
        const int slice = (sp - 1) * 4 + qg;
        uint32_t* ox = &OxP[slice][0];
#pragma unroll
        for (int nt = 0; nt < 4; ++nt) {
#pragma unroll
            for (int rp = 0; rp < 2; ++rp)
                ox[(quad * 2 + rp) * OXW + nt * 16 + col] =
                    cvt2bf(o[nt][2 * rp], o[nt][2 * rp + 1]);
        }
        if (quad == 0) Lx[slice * 16 + col] = lsum;
    }
    __syncthreads();   // full barrier: OxP/Lx cross-wave publish (once)
    if (sp == 0) {
        float ltot = lsum;
#pragma unroll
        for (int s = 0; s < 3; ++s)
            ltot += Lx[(s * 4 + qg) * 16 + col];
        float linv[4];
#pragma unroll
        for (int r = 0; r < 4; ++r)
            linv[r] = 1.0f / __shfl(ltot, quad * 4 + r, 16);

#pragma unroll
        for (int s = 0; s < 3; ++s) {
            const uint32_t* ox = &OxP[s * 4 + qg][0];
#pragma unroll
            for (int nt = 0; nt < 4; ++nt) {
#pragma unroll
                for (int rp = 0; rp < 2; ++rp) {
                    uint32_t u = ox[(quad * 2 + rp) * OXW + nt * 16 + col];
                    o[nt][2 * rp]     += bflo2f(u);
                    o[nt][2 * rp + 1] += bfhi2f(u);
                }
            }
        }
        const float g = gamma[0];
#pragma unroll
        for (int nt = 0; nt < 4; ++nt) {
            const int c = nt * 16 + col;
#pragma unroll
            for (int r = 0; r < 4; ++r) {
                const int i = iw + quad * 4 + r;
                const size_t idx = ((size_t)(b * 64 + c)) * 4096 + i;
                out[idx] = g * (o[nt][r] * linv[r]) + x[idx];
            }
        }
    }
}

// ---------------------------------------------------------------------------
extern "C" void kernel_launch(void* const* d_in, const int* in_sizes, int n_in,
                              void* d_out, int out_size, void* d_ws, size_t ws_size,
                              hipStream_t stream)
{
    const float* x     = (const float*)d_in[0];
    const float* Wq    = (const float*)d_in[1];
    const float* bq    = (const float*)d_in[2];
    const float* Wk    = (const float*)d_in[3];
    const float* bk    = (const float*)d_in[4];
    const float* Wv    = (const float*)d_in[5];
    const float* bv    = (const float*)d_in[6];
    const float* gamma = (const float*)d_in[7];

    u16* QT = (u16*)d_ws;                 // [4][4096][8]  bf16
    u16* KT = QT + (size_t)4 * 4096 * 8;  // [4][4096][8]  bf16
    u8*  Vg = (u8*)(KT + (size_t)4 * 4096 * 8);  // [4][64][4096] fp8 e4m3

    qkv_kernel<<<1280, 256, 0, stream>>>(x, Wq, bq, Wk, bk, Wv, bv, QT, KT, Vg);
    attn_kernel<<<256, 1024, 0, stream>>>(QT, KT, Vg, x, gamma, (float*)d_out);
}